// Round 6
// baseline (749.223 us; speedup 1.0000x reference)
//
#include <hip/hip_runtime.h>

// ---------------------------------------------------------------------------
// BikeSafetyGNN: 3-layer GraphSAGE (mean) + 2 linear heads, fp32.
// R15: fix R14's residual-read index bug: R4[n*L/4+cl] parsed as (n*L)/4
//      (and was semantically wrong anyway) -> R4[n*L+cl]. Same in gather_head.
// R14: (a) k_wprep pre-converts ALL weights to bf16 hi/lo triplets in global
//      once (~64KB, L2-hot). proj_mfma loses its 52KB LDS weight stage and
//      per-block convert VALU; gather_proj epilogues lose per-wave weight
//      reload+convert. Bit-identical numerics (same RNE converts).
//      (b) gathers launch_bounds(256,8) for more resident waves.
//      (c) 32-bit P-index math.
// R13: gather+proj fusion (h1/h2 never hit HBM), head fusion in final gather.
// R9:  uint2 gather shape (16 lanes x 8 B = full row/node), T packed 4 B/edge.
// ---------------------------------------------------------------------------

typedef __bf16 bf16x8 __attribute__((ext_vector_type(8)));
typedef float  f32x4  __attribute__((ext_vector_type(4)));

__device__ __forceinline__ unsigned short f2bf_rne(float f) {
    unsigned int u = __float_as_uint(f);
    u = (u + 0x7FFFu + ((u >> 16) & 1u)) >> 16;
    return (unsigned short)u;
}

// unpack 4 bf16 (packed little-endian in uint2) and accumulate into float4
__device__ __forceinline__ void bfacc(float4& a, const uint2 q) {
    a.x += __uint_as_float(q.x << 16);
    a.y += __uint_as_float(q.x & 0xFFFF0000u);
    a.z += __uint_as_float(q.y << 16);
    a.w += __uint_as_float(q.y & 0xFFFF0000u);
}

// ---------------- weight pre-conversion (once, ~64KB) ----------------
// layout in O (__bf16): [0]=W1l, [8192]=W1rh, [16384]=W1rl,
// [24576]=W2l, [26624]=W2rh, [28672]=W2rl, [30720]=W3l, [31232]=W3rh, [31744]=W3rl
__global__ __launch_bounds__(256) void k_wprep(const float* __restrict__ W1l,
                                               const float* __restrict__ W1r,
                                               const float* __restrict__ W2l,
                                               const float* __restrict__ W2r,
                                               const float* __restrict__ W3l,
                                               const float* __restrict__ W3r,
                                               __bf16* __restrict__ O) {
    int i = blockIdx.x * 256 + threadIdx.x;   // 0..10751
    const float *Wl, *Wr; __bf16* base; int idx, n;
    if (i < 8192)       { Wl = W1l; Wr = W1r; base = O;         idx = i;         n = 8192; }
    else if (i < 10240) { Wl = W2l; Wr = W2r; base = O + 24576; idx = i - 8192;  n = 2048; }
    else if (i < 10752) { Wl = W3l; Wr = W3r; base = O + 30720; idx = i - 10240; n = 512; }
    else return;
    float wl = Wl[idx], wr = Wr[idx];
    __bf16 h = (__bf16)wr;
    base[idx]         = (__bf16)wl;
    base[n + idx]     = h;
    base[2 * n + idx] = (__bf16)(wr - (float)h);
}

// ---------------- CSR build (bucket = dst >> 10) ----------------

__global__ __launch_bounds__(256) void k_bcount(const int* __restrict__ dst, int E, int N,
                                                int* __restrict__ bcnt) {
    __shared__ int h[256];
    const int tid = threadIdx.x;
    h[tid] = 0;
    __syncthreads();
    const int stride = gridDim.x * 256;
    for (int i = blockIdx.x * 256 + tid; i < E; i += stride) {
        int d = dst[i];
        d = d < 0 ? 0 : (d >= N ? N - 1 : d);
        atomicAdd(&h[d >> 10], 1);
    }
    __syncthreads();
    if (h[tid]) atomicAdd(&bcnt[tid], h[tid]);
}

__global__ __launch_bounds__(256) void k_bscan(const int* __restrict__ bcnt,
                                               int* __restrict__ boff,
                                               int* __restrict__ bcur, int NBK, int E) {
    __shared__ int sd[256];
    const int tid = threadIdx.x;
    bcur[tid] = 0;                            // folded memset
    int v = (tid < NBK) ? bcnt[tid] : 0;
    sd[tid] = v; __syncthreads();
    for (int off = 1; off < 256; off <<= 1) {
        int t = (tid >= off) ? sd[tid - off] : 0;
        __syncthreads();
        sd[tid] += t;
        __syncthreads();
    }
    if (tid < NBK) boff[tid] = sd[tid] - v;   // exclusive
    if (tid == 0) boff[NBK] = E;
}

// tile-local LDS counting sort; T entry = (dloc<<18) | src  (4 B/edge)
#define BTILE 4096
__global__ __launch_bounds__(256) void k_bucket(const int* __restrict__ src,
                                                const int* __restrict__ dst, int E, int N,
                                                const int* __restrict__ boff,
                                                int* __restrict__ bcur,
                                                int* __restrict__ T, int NBK) {
    __shared__ int cnt[256], cnt2[256], lofs[256], gbase[256], boffs[256], sd[256];
    __shared__ int2 staged[BTILE];
    const int tid = threadIdx.x;
    const int tb = blockIdx.x * BTILE;
    const int tn = min(BTILE, E - tb);
    cnt[tid] = 0; cnt2[tid] = 0;
    boffs[tid] = (tid < NBK) ? boff[tid] : 0;
    __syncthreads();
    for (int i = tid; i < tn; i += 256) {
        int d = dst[tb + i];
        d = d < 0 ? 0 : (d >= N ? N - 1 : d);
        atomicAdd(&cnt[d >> 10], 1);
    }
    __syncthreads();
    int v = cnt[tid];
    sd[tid] = v; __syncthreads();
    for (int off = 1; off < 256; off <<= 1) {
        int t = (tid >= off) ? sd[tid - off] : 0;
        __syncthreads();
        sd[tid] += t;
        __syncthreads();
    }
    lofs[tid] = sd[tid] - v;
    if (v > 0 && tid < NBK) gbase[tid] = atomicAdd(&bcur[tid], v);
    __syncthreads();
    for (int i = tid; i < tn; i += 256) {
        int d = dst[tb + i];
        d = d < 0 ? 0 : (d >= N ? N - 1 : d);
        int s = src[tb + i];
        s = s < 0 ? 0 : (s >= N ? N - 1 : s);
        int b = d >> 10;
        int r = atomicAdd(&cnt2[b], 1);
        staged[lofs[b] + r] = make_int2(s, d);
    }
    __syncthreads();
    for (int i = tid; i < tn; i += 256) {
        int2 p = staged[i];
        int b = p.y >> 10;
        T[(size_t)boffs[b] + gbase[b] + (i - lofs[b])] = ((p.y & 1023) << 18) | p.x;
    }
}

// per bucket: LDS degree histogram + 1024-wide scan -> rowptr, then LDS-cursor
// fill of adj (packed T: dloc = p>>18, src = p & 0x3FFFF)
__global__ __launch_bounds__(1024) void k_csr(const int* __restrict__ T,
                                              const int* __restrict__ boff,
                                              int* __restrict__ rowptr,
                                              int* __restrict__ adj, int N, int E) {
    __shared__ int hist[1024];
    __shared__ int sc[1024];
    const int tid = threadIdx.x;
    const int b = blockIdx.x;
    const int node0 = b << 10;
    hist[tid] = 0;
    __syncthreads();
    const int beg = boff[b], end = boff[b + 1];
    for (int i = beg + tid; i < end; i += 1024)
        atomicAdd(&hist[((unsigned)T[i]) >> 18], 1);
    __syncthreads();
    int v = hist[tid];
    sc[tid] = v;
    __syncthreads();
    for (int off = 1; off < 1024; off <<= 1) {
        int t = (tid >= off) ? sc[tid - off] : 0;
        __syncthreads();
        sc[tid] += t;
        __syncthreads();
    }
    const int excl = beg + sc[tid] - v;
    const int n = node0 + tid;
    if (n < N) rowptr[n] = excl;
    if (b == 0 && tid == 0) rowptr[N] = E;
    hist[tid] = excl;
    __syncthreads();
    for (int i = beg + tid; i < end; i += 1024) {
        unsigned p = (unsigned)T[i];
        int pos = atomicAdd(&hist[p >> 18], 1);
        adj[pos] = (int)(p & 0x3FFFFu);
    }
}

// ---------------- MFMA projection (layer 1): weights pre-converted, no LDS ----
template<int DIN, int DOUT>
__global__ __launch_bounds__(256, 6) void proj_mfma(const float* __restrict__ H,
                                                    const __bf16* __restrict__ Wlb,
                                                    const __bf16* __restrict__ Wrh,
                                                    const __bf16* __restrict__ Wrl,
                                                    const float* __restrict__ bias,
                                                    unsigned short* __restrict__ Pl,
                                                    float* __restrict__ R, int N) {
    constexpr int COLT = DOUT / 16;
    const int wave = threadIdx.x >> 6, lane = threadIdx.x & 63;
    const int quad = lane >> 4, l16 = lane & 15;
    const int n0 = (blockIdx.x * 4 + wave) * 16;
    int arow = n0 + l16;
    if (arow >= N) arow = N - 1;
    const float* hrow = H + (size_t)arow * DIN;

    f32x4 zero = {0.f, 0.f, 0.f, 0.f};
    f32x4 accP[COLT], accR[COLT];
    #pragma unroll
    for (int t = 0; t < COLT; ++t) { accP[t] = zero; accR[t] = zero; }

    for (int k0 = 0; k0 < DIN; k0 += 32) {
        const float* hp = hrow + k0 + quad * 8;
        float4 h0 = *(const float4*)hp;
        float4 h1 = *(const float4*)(hp + 4);
        float hv[8] = {h0.x, h0.y, h0.z, h0.w, h1.x, h1.y, h1.z, h1.w};
        bf16x8 ahi, alo;
        #pragma unroll
        for (int j = 0; j < 8; ++j) {
            __bf16 hb = (__bf16)hv[j];
            ahi[j] = hb;
            alo[j] = (__bf16)(hv[j] - (float)hb);
        }
        const int kk = k0 + quad * 8;
        #pragma unroll
        for (int t = 0; t < COLT; ++t) {
            const int c = t * 16 + l16;
            bf16x8 bl  = *(const bf16x8*)&Wlb[c * DIN + kk];
            bf16x8 brh = *(const bf16x8*)&Wrh[c * DIN + kk];
            bf16x8 brl = *(const bf16x8*)&Wrl[c * DIN + kk];
            accP[t] = __builtin_amdgcn_mfma_f32_16x16x32_bf16(ahi, bl,  accP[t], 0, 0, 0);
            accR[t] = __builtin_amdgcn_mfma_f32_16x16x32_bf16(ahi, brh, accR[t], 0, 0, 0);
            accR[t] = __builtin_amdgcn_mfma_f32_16x16x32_bf16(ahi, brl, accR[t], 0, 0, 0);
            accR[t] = __builtin_amdgcn_mfma_f32_16x16x32_bf16(alo, brh, accR[t], 0, 0, 0);
        }
    }
    // C/D layout: col = lane&15, row = quad*4 + reg  [m89-verified]
    #pragma unroll
    for (int t = 0; t < COLT; ++t) {
        const int c = t * 16 + l16;
        const float bc = bias[c];
        #pragma unroll
        for (int r = 0; r < 4; ++r) {
            int node = n0 + quad * 4 + r;
            if (node < N) {
                Pl[(size_t)node * DOUT + c] = f2bf_rne(accP[t][r]);
                R[(size_t)node * DOUT + c] = accR[t][r] + bc;
            }
        }
    }
}

// ---------------- fused gather + next-layer projection ----------------
// gather phase: h[n] = relu( mean_j P[adj] + Rres[n] )   (h staged in LDS)
// proj phase:   Pout[n] = bf16( h W_l^T ),  Rout[n] = h W_r^T + b  (MFMA)
template<int D, int DP>
__global__ __launch_bounds__(256, 8) void gather_proj(const unsigned short* __restrict__ P,
                                                      const int* __restrict__ rowptr,
                                                      const int* __restrict__ adj,
                                                      const float* __restrict__ Rres,
                                                      const __bf16* __restrict__ Wlb,
                                                      const __bf16* __restrict__ Wrh,
                                                      const __bf16* __restrict__ Wrl,
                                                      const float* __restrict__ bias,
                                                      unsigned short* __restrict__ Pout,
                                                      float* __restrict__ Rout, int N) {
    constexpr int L   = D / 4;     // uint2s (4 bf16) per node row
    constexpr int S   = 64 / L;    // nodes concurrently per wave
    constexpr int M   = 4;         // sequential nodes per subgroup
    constexpr int NPW = S * M;     // nodes per wave
    constexpr int NPB = NPW * 4;   // nodes per block (4 waves)
    constexpr int SP  = D + 4;     // LDS row stride (floats, 16B-aligned, pad)
    constexpr int COLT = DP / 16;
    __shared__ __align__(16) float hstage[NPB * SP];

    const int wave = threadIdx.x >> 6, lane = threadIdx.x & 63;
    const int sub = lane / L, cl = lane % L;
    const uint2* __restrict__ P2 = (const uint2*)P;
    const f32x4* __restrict__ R4 = (const f32x4*)Rres;
    const int base = blockIdx.x * NPB + wave * NPW + sub;

    // ---- gather phase ----
    #pragma unroll 1
    for (int m = 0; m < M; ++m) {
        const int n = base + m * S;
        const int lrow = wave * NPW + sub + m * S;   // local row in block
        f32x4 o = {0.f, 0.f, 0.f, 0.f};
        if (n < N) {
            int beg = rowptr[n], end = rowptr[n + 1];
            float4 a0 = {0, 0, 0, 0}, a1 = {0, 0, 0, 0}, a2 = {0, 0, 0, 0}, a3 = {0, 0, 0, 0};
            int j = beg;
            while (j < end && (j & 3)) { bfacc(a0, P2[adj[j] * L + cl]); ++j; }
            for (; j + 8 <= end; j += 8) {
                int4 sA = *(const int4*)(adj + j);
                int4 sB = *(const int4*)(adj + j + 4);
                uint2 p0 = P2[sA.x * L + cl];
                uint2 p1 = P2[sA.y * L + cl];
                uint2 p2 = P2[sA.z * L + cl];
                uint2 p3 = P2[sA.w * L + cl];
                uint2 p4 = P2[sB.x * L + cl];
                uint2 p5 = P2[sB.y * L + cl];
                uint2 p6 = P2[sB.z * L + cl];
                uint2 p7 = P2[sB.w * L + cl];
                bfacc(a0, p0); bfacc(a1, p1); bfacc(a2, p2); bfacc(a3, p3);
                bfacc(a0, p4); bfacc(a1, p5); bfacc(a2, p6); bfacc(a3, p7);
            }
            if (j + 4 <= end) {
                int4 sA = *(const int4*)(adj + j);
                bfacc(a0, P2[sA.x * L + cl]);
                bfacc(a1, P2[sA.y * L + cl]);
                bfacc(a2, P2[sA.z * L + cl]);
                bfacc(a3, P2[sA.w * L + cl]);
                j += 4;
            }
            for (; j < end; ++j) bfacc(a0, P2[adj[j] * L + cl]);
            int deg = end - beg;
            float inv = deg > 0 ? 1.0f / (float)deg : 0.0f;
            f32x4 r = R4[(size_t)n * L + cl];
            o.x = fmaxf((a0.x + a1.x + a2.x + a3.x) * inv + r.x, 0.0f);
            o.y = fmaxf((a0.y + a1.y + a2.y + a3.y) * inv + r.y, 0.0f);
            o.z = fmaxf((a0.z + a1.z + a2.z + a3.z) * inv + r.z, 0.0f);
            o.w = fmaxf((a0.w + a1.w + a2.w + a3.w) * inv + r.w, 0.0f);
        }
        *(f32x4*)&hstage[lrow * SP + cl * 4] = o;
    }
    __syncthreads();

    // ---- proj phase: NPB nodes, DIN=D -> DOUT=DP, A from LDS, W pre-converted ----
    const int quad = lane >> 4, l16 = lane & 15;
    f32x4 zero = {0.f, 0.f, 0.f, 0.f};
    #pragma unroll
    for (int tile = 0; tile < NPB / 64; ++tile) {
        const int trow0 = wave * NPW + tile * 16;     // tile's first local row
        f32x4 accP[COLT], accR[COLT];
        #pragma unroll
        for (int t = 0; t < COLT; ++t) { accP[t] = zero; accR[t] = zero; }
        #pragma unroll
        for (int k0 = 0; k0 < D; k0 += 32) {
            const int kk = k0 + quad * 8;
            const float* hp = &hstage[(trow0 + l16) * SP + kk];
            f32x4 h0 = *(const f32x4*)hp;
            f32x4 h1 = *(const f32x4*)(hp + 4);
            float hv[8] = {h0.x, h0.y, h0.z, h0.w, h1.x, h1.y, h1.z, h1.w};
            bf16x8 ahi, alo;
            #pragma unroll
            for (int j = 0; j < 8; ++j) {
                __bf16 hb = (__bf16)hv[j];
                ahi[j] = hb;
                alo[j] = (__bf16)(hv[j] - (float)hb);
            }
            #pragma unroll
            for (int t = 0; t < COLT; ++t) {
                const int c = t * 16 + l16;
                bf16x8 bl  = *(const bf16x8*)&Wlb[c * D + kk];
                bf16x8 brh = *(const bf16x8*)&Wrh[c * D + kk];
                bf16x8 brl = *(const bf16x8*)&Wrl[c * D + kk];
                accP[t] = __builtin_amdgcn_mfma_f32_16x16x32_bf16(ahi, bl,  accP[t], 0, 0, 0);
                accR[t] = __builtin_amdgcn_mfma_f32_16x16x32_bf16(ahi, brh, accR[t], 0, 0, 0);
                accR[t] = __builtin_amdgcn_mfma_f32_16x16x32_bf16(ahi, brl, accR[t], 0, 0, 0);
                accR[t] = __builtin_amdgcn_mfma_f32_16x16x32_bf16(alo, brh, accR[t], 0, 0, 0);
            }
        }
        // C/D layout: col = lane&15, row = quad*4 + reg  [m89-verified]
        #pragma unroll
        for (int t = 0; t < COLT; ++t) {
            const int c = t * 16 + l16;
            const float bc = bias[c];
            #pragma unroll
            for (int r = 0; r < 4; ++r) {
                int node = blockIdx.x * NPB + trow0 + quad * 4 + r;
                if (node < N) {
                    Pout[(size_t)node * DP + c] = f2bf_rne(accP[t][r]);
                    Rout[(size_t)node * DP + c] = accR[t][r] + bc;
                }
            }
        }
    }
}

// ---------------- final gather + linear heads (layer 3) ----------------

template<int DOUT> struct GatherCfg {
    static constexpr int L   = DOUT / 4;   // uint2s (4 bf16) per node row
    static constexpr int S   = 64 / L;     // nodes concurrently per wave
    static constexpr int M   = 4;          // sequential nodes per subgroup
    static constexpr int NPW = S * M;
    static constexpr int NPB = NPW * 4;    // 4 waves/block
};

template<int DOUT>
__global__ __launch_bounds__(256, 8) void gather_head(const unsigned short* __restrict__ P,
                                                      const int* __restrict__ rowptr,
                                                      const int* __restrict__ adj,
                                                      const float* __restrict__ Rres, int N,
                                                      const float* __restrict__ Wreg,
                                                      const float* __restrict__ breg,
                                                      const float* __restrict__ Wcls,
                                                      const float* __restrict__ bcls,
                                                      float* __restrict__ out) {
    using C = GatherCfg<DOUT>;
    constexpr int L = C::L, S = C::S, M = C::M;
    constexpr int NPW = C::NPW, NPB = C::NPB;
    const int wave = threadIdx.x >> 6, lane = threadIdx.x & 63;
    const int sub = lane / L, cl = lane % L;
    const uint2* __restrict__ P2 = (const uint2*)P;
    const float4* __restrict__ R4 = (const float4*)Rres;
    const int base = blockIdx.x * NPB + wave * NPW + sub;
    #pragma unroll 1
    for (int m = 0; m < M; ++m) {
        int n = base + m * S;
        if (n >= N) continue;
        int beg = rowptr[n], end = rowptr[n + 1];
        float4 a0 = {0, 0, 0, 0}, a1 = {0, 0, 0, 0}, a2 = {0, 0, 0, 0}, a3 = {0, 0, 0, 0};
        int j = beg;
        while (j < end && (j & 3)) { bfacc(a0, P2[adj[j] * L + cl]); ++j; }
        for (; j + 8 <= end; j += 8) {
            int4 sA = *(const int4*)(adj + j);
            int4 sB = *(const int4*)(adj + j + 4);
            uint2 p0 = P2[sA.x * L + cl];
            uint2 p1 = P2[sA.y * L + cl];
            uint2 p2 = P2[sA.z * L + cl];
            uint2 p3 = P2[sA.w * L + cl];
            uint2 p4 = P2[sB.x * L + cl];
            uint2 p5 = P2[sB.y * L + cl];
            uint2 p6 = P2[sB.z * L + cl];
            uint2 p7 = P2[sB.w * L + cl];
            bfacc(a0, p0); bfacc(a1, p1); bfacc(a2, p2); bfacc(a3, p3);
            bfacc(a0, p4); bfacc(a1, p5); bfacc(a2, p6); bfacc(a3, p7);
        }
        if (j + 4 <= end) {
            int4 sA = *(const int4*)(adj + j);
            bfacc(a0, P2[sA.x * L + cl]);
            bfacc(a1, P2[sA.y * L + cl]);
            bfacc(a2, P2[sA.z * L + cl]);
            bfacc(a3, P2[sA.w * L + cl]);
            j += 4;
        }
        for (; j < end; ++j) bfacc(a0, P2[adj[j] * L + cl]);
        int deg = end - beg;
        float inv = deg > 0 ? 1.0f / (float)deg : 0.0f;
        float4 r = R4[(size_t)n * L + cl];
        float4 o;
        o.x = fmaxf((a0.x + a1.x + a2.x + a3.x) * inv + r.x, 0.0f);
        o.y = fmaxf((a0.y + a1.y + a2.y + a3.y) * inv + r.y, 0.0f);
        o.z = fmaxf((a0.z + a1.z + a2.z + a3.z) * inv + r.z, 0.0f);
        o.w = fmaxf((a0.w + a1.w + a2.w + a3.w) * inv + r.w, 0.0f);
        // fused linear heads: per-lane partial dot (4 of 16 features),
        // 2-step shfl reduce across the 4-lane subgroup
        float4 wr = ((const float4*)Wreg)[cl];
        float4 wc = ((const float4*)Wcls)[cl];
        float pr = o.x * wr.x + o.y * wr.y + o.z * wr.z + o.w * wr.w;
        float pc = o.x * wc.x + o.y * wc.y + o.z * wc.z + o.w * wc.w;
        pr += __shfl_xor(pr, 1); pr += __shfl_xor(pr, 2);
        pc += __shfl_xor(pc, 1); pc += __shfl_xor(pc, 2);
        if (cl == 0) {
            out[n] = pr + breg[0];
            out[(size_t)N + n] = pc + bcls[0];
        }
    }
}

extern "C" void kernel_launch(void* const* d_in, const int* in_sizes, int n_in,
                              void* d_out, int out_size, void* d_ws, size_t ws_size,
                              hipStream_t stream) {
    const float* x    = (const float*)d_in[0];
    const int*   ei   = (const int*)d_in[1];
    const float* W1l  = (const float*)d_in[2];
    const float* b1l  = (const float*)d_in[3];
    const float* W1r  = (const float*)d_in[4];
    const float* W2l  = (const float*)d_in[5];
    const float* b2l  = (const float*)d_in[6];
    const float* W2r  = (const float*)d_in[7];
    const float* W3l  = (const float*)d_in[8];
    const float* b3l  = (const float*)d_in[9];
    const float* W3r  = (const float*)d_in[10];
    const float* Wreg = (const float*)d_in[11];
    const float* breg = (const float*)d_in[12];
    const float* Wcls = (const float*)d_in[13];
    const float* bcls = (const float*)d_in[14];

    const int N = in_sizes[0] / 128;
    const int E = in_sizes[1] / 2;
    const int* src = ei;
    const int* dst = ei + E;

    char* ws = (char*)d_ws;
    size_t off = 0;
    auto alloc = [&](size_t bytes) -> void* {
        void* p = ws + off;
        off += (bytes + 255) & ~(size_t)255;
        return p;
    };
    int*   rowptr = (int*)alloc((size_t)(N + 1) * 4);
    int*   bcnt   = (int*)alloc(1024);
    int*   bcur   = (int*)alloc(1024);
    int*   boff   = (int*)alloc(1028);
    int*   adj    = (int*)alloc((size_t)E * 4);
    __bf16* W16   = (__bf16*)alloc(32256 * 2);           // pre-converted weights
    unsigned short* A1 = (unsigned short*)alloc((size_t)N * 64 * 2);  // P1 bf16; A3 aliases
    unsigned short* A2 = (unsigned short*)alloc((size_t)N * 32 * 2);  // P2 bf16
    float* B      = (float*)alloc((size_t)N * 64 * 4);  // R1; doubles as T during CSR build
    float* C      = (float*)alloc((size_t)N * 32 * 4);  // R2
    float* D      = (float*)alloc((size_t)N * 16 * 4);  // R3
    int*   T      = (int*)B;                             // packed edges, E*4B <= N*64*4B
    unsigned short* A3 = A1;                             // P3 bf16 (A1 dead after layer 2)

    const int NBK = (N + 1023) >> 10;     // buckets (196; must be <= 256)

    // ---- weight pre-conversion (independent of everything else) ----
    k_wprep<<<42, 256, 0, stream>>>(W1l, W1r, W2l, W2r, W3l, W3r, W16);

    // ---- CSR build ----
    hipMemsetAsync(bcnt, 0, 1024, stream);
    k_bcount<<<1024, 256, 0, stream>>>(dst, E, N, bcnt);
    k_bscan<<<1, 256, 0, stream>>>(bcnt, boff, bcur, NBK, E);
    k_bucket<<<(E + BTILE - 1) / BTILE, 256, 0, stream>>>(src, dst, E, N, boff, bcur, T, NBK);
    k_csr<<<NBK, 1024, 0, stream>>>(T, boff, rowptr, adj, N, E);

    const int PB = 64;   // nodes per proj_mfma block (4 waves x 16)

    // ---- layer 1 projection: x (128) -> P1,R1 (64) ----
    proj_mfma<128, 64><<<(N + PB - 1) / PB, 256, 0, stream>>>(
        x, W16, W16 + 8192, W16 + 16384, b1l, A1, B, N);
    // ---- layer 1 gather + layer 2 projection fused: h1 never hits HBM ----
    gather_proj<64, 32><<<(N + 63) / 64, 256, 0, stream>>>(
        A1, rowptr, adj, B, W16 + 24576, W16 + 26624, W16 + 28672, b2l, A2, C, N);
    // ---- layer 2 gather + layer 3 projection fused: h2 never hits HBM ----
    gather_proj<32, 16><<<(N + 127) / 128, 256, 0, stream>>>(
        A2, rowptr, adj, C, W16 + 30720, W16 + 31232, W16 + 31744, b3l, A3, D, N);
    // ---- layer 3 gather + linear heads fused ----
    constexpr int G16 = GatherCfg<16>::NPB;
    gather_head<16><<<(N + G16 - 1) / G16, 256, 0, stream>>>(
        A3, rowptr, adj, D, N, Wreg, breg, Wcls, bcls, (float*)d_out);
}

// Round 7
// 695.323 us; speedup vs baseline: 1.0775x; 1.0775x over previous
//
#include <hip/hip_runtime.h>

// ---------------------------------------------------------------------------
// BikeSafetyGNN: 3-layer GraphSAGE (mean) + 2 linear heads, fp32.
// R16: R15's no-LDS proj_mfma had LANE-SCATTERED weight reads (lane l16 ->
//      row c -> 16 different cache lines per 16B fragment load) on the MFMA
//      critical path + an 84-VGPR cap (256,6) -> suspected cause of the
//      708->749 regression. Fix: k_wprep writes MFMA-fragment-packed layout
//      W[u][c][8] (u = k/8) so a quad's 16 lanes read 256B CONTIGUOUS.
//      proj_mfma back to plain launch_bounds(256), still zero LDS.
//      Same packed reads in both gather_proj epilogues. Numerics identical.
// R15: residual-index fix; k_wprep bf16 hi/lo pre-conversion; gathers (256,8);
//      32-bit P-index math.
// R13: gather+proj fusion (h1/h2 never hit HBM), head fusion in final gather.
// R9:  uint2 gather shape (16 lanes x 8 B = full row/node), T packed 4 B/edge.
// ---------------------------------------------------------------------------

typedef __bf16 bf16x8 __attribute__((ext_vector_type(8)));
typedef float  f32x4  __attribute__((ext_vector_type(4)));

__device__ __forceinline__ unsigned short f2bf_rne(float f) {
    unsigned int u = __float_as_uint(f);
    u = (u + 0x7FFFu + ((u >> 16) & 1u)) >> 16;
    return (unsigned short)u;
}

// unpack 4 bf16 (packed little-endian in uint2) and accumulate into float4
__device__ __forceinline__ void bfacc(float4& a, const uint2 q) {
    a.x += __uint_as_float(q.x << 16);
    a.y += __uint_as_float(q.x & 0xFFFF0000u);
    a.z += __uint_as_float(q.y << 16);
    a.w += __uint_as_float(q.y & 0xFFFF0000u);
}

// ---------------- weight pre-conversion (once, ~64KB), MFMA-packed ----------
// For each layer (DIN,DOUT): pos = ((k/8)*DOUT + c)*8 + (k%8), idx = c*DIN+k.
// O (__bf16): [0]=W1l, [8192]=W1rh, [16384]=W1rl,
// [24576]=W2l, [26624]=W2rh, [28672]=W2rl, [30720]=W3l, [31232]=W3rh, [31744]=W3rl
__global__ __launch_bounds__(256) void k_wprep(const float* __restrict__ W1l,
                                               const float* __restrict__ W1r,
                                               const float* __restrict__ W2l,
                                               const float* __restrict__ W2r,
                                               const float* __restrict__ W3l,
                                               const float* __restrict__ W3r,
                                               __bf16* __restrict__ O) {
    int i = blockIdx.x * 256 + threadIdx.x;   // 0..10751
    const float *Wl, *Wr; __bf16* base; int idx, n, DIN, DOUT;
    if (i < 8192)       { Wl = W1l; Wr = W1r; base = O;         idx = i;         n = 8192; DIN = 128; DOUT = 64; }
    else if (i < 10240) { Wl = W2l; Wr = W2r; base = O + 24576; idx = i - 8192;  n = 2048; DIN = 64;  DOUT = 32; }
    else if (i < 10752) { Wl = W3l; Wr = W3r; base = O + 30720; idx = i - 10240; n = 512;  DIN = 32;  DOUT = 16; }
    else return;
    int c = idx / DIN, k = idx % DIN;
    int pos = ((k >> 3) * DOUT + c) * 8 + (k & 7);
    float wl = Wl[idx], wr = Wr[idx];
    __bf16 h = (__bf16)wr;
    base[pos]         = (__bf16)wl;
    base[n + pos]     = h;
    base[2 * n + pos] = (__bf16)(wr - (float)h);
}

// ---------------- CSR build (bucket = dst >> 10) ----------------

__global__ __launch_bounds__(256) void k_bcount(const int* __restrict__ dst, int E, int N,
                                                int* __restrict__ bcnt) {
    __shared__ int h[256];
    const int tid = threadIdx.x;
    h[tid] = 0;
    __syncthreads();
    const int stride = gridDim.x * 256;
    for (int i = blockIdx.x * 256 + tid; i < E; i += stride) {
        int d = dst[i];
        d = d < 0 ? 0 : (d >= N ? N - 1 : d);
        atomicAdd(&h[d >> 10], 1);
    }
    __syncthreads();
    if (h[tid]) atomicAdd(&bcnt[tid], h[tid]);
}

__global__ __launch_bounds__(256) void k_bscan(const int* __restrict__ bcnt,
                                               int* __restrict__ boff,
                                               int* __restrict__ bcur, int NBK, int E) {
    __shared__ int sd[256];
    const int tid = threadIdx.x;
    bcur[tid] = 0;                            // folded memset
    int v = (tid < NBK) ? bcnt[tid] : 0;
    sd[tid] = v; __syncthreads();
    for (int off = 1; off < 256; off <<= 1) {
        int t = (tid >= off) ? sd[tid - off] : 0;
        __syncthreads();
        sd[tid] += t;
        __syncthreads();
    }
    if (tid < NBK) boff[tid] = sd[tid] - v;   // exclusive
    if (tid == 0) boff[NBK] = E;
}

// tile-local LDS counting sort; T entry = (dloc<<18) | src  (4 B/edge)
#define BTILE 4096
__global__ __launch_bounds__(256) void k_bucket(const int* __restrict__ src,
                                                const int* __restrict__ dst, int E, int N,
                                                const int* __restrict__ boff,
                                                int* __restrict__ bcur,
                                                int* __restrict__ T, int NBK) {
    __shared__ int cnt[256], cnt2[256], lofs[256], gbase[256], boffs[256], sd[256];
    __shared__ int2 staged[BTILE];
    const int tid = threadIdx.x;
    const int tb = blockIdx.x * BTILE;
    const int tn = min(BTILE, E - tb);
    cnt[tid] = 0; cnt2[tid] = 0;
    boffs[tid] = (tid < NBK) ? boff[tid] : 0;
    __syncthreads();
    for (int i = tid; i < tn; i += 256) {
        int d = dst[tb + i];
        d = d < 0 ? 0 : (d >= N ? N - 1 : d);
        atomicAdd(&cnt[d >> 10], 1);
    }
    __syncthreads();
    int v = cnt[tid];
    sd[tid] = v; __syncthreads();
    for (int off = 1; off < 256; off <<= 1) {
        int t = (tid >= off) ? sd[tid - off] : 0;
        __syncthreads();
        sd[tid] += t;
        __syncthreads();
    }
    lofs[tid] = sd[tid] - v;
    if (v > 0 && tid < NBK) gbase[tid] = atomicAdd(&bcur[tid], v);
    __syncthreads();
    for (int i = tid; i < tn; i += 256) {
        int d = dst[tb + i];
        d = d < 0 ? 0 : (d >= N ? N - 1 : d);
        int s = src[tb + i];
        s = s < 0 ? 0 : (s >= N ? N - 1 : s);
        int b = d >> 10;
        int r = atomicAdd(&cnt2[b], 1);
        staged[lofs[b] + r] = make_int2(s, d);
    }
    __syncthreads();
    for (int i = tid; i < tn; i += 256) {
        int2 p = staged[i];
        int b = p.y >> 10;
        T[(size_t)boffs[b] + gbase[b] + (i - lofs[b])] = ((p.y & 1023) << 18) | p.x;
    }
}

// per bucket: LDS degree histogram + 1024-wide scan -> rowptr, then LDS-cursor
// fill of adj (packed T: dloc = p>>18, src = p & 0x3FFFF)
__global__ __launch_bounds__(1024) void k_csr(const int* __restrict__ T,
                                              const int* __restrict__ boff,
                                              int* __restrict__ rowptr,
                                              int* __restrict__ adj, int N, int E) {
    __shared__ int hist[1024];
    __shared__ int sc[1024];
    const int tid = threadIdx.x;
    const int b = blockIdx.x;
    const int node0 = b << 10;
    hist[tid] = 0;
    __syncthreads();
    const int beg = boff[b], end = boff[b + 1];
    for (int i = beg + tid; i < end; i += 1024)
        atomicAdd(&hist[((unsigned)T[i]) >> 18], 1);
    __syncthreads();
    int v = hist[tid];
    sc[tid] = v;
    __syncthreads();
    for (int off = 1; off < 1024; off <<= 1) {
        int t = (tid >= off) ? sc[tid - off] : 0;
        __syncthreads();
        sc[tid] += t;
        __syncthreads();
    }
    const int excl = beg + sc[tid] - v;
    const int n = node0 + tid;
    if (n < N) rowptr[n] = excl;
    if (b == 0 && tid == 0) rowptr[N] = E;
    hist[tid] = excl;
    __syncthreads();
    for (int i = beg + tid; i < end; i += 1024) {
        unsigned p = (unsigned)T[i];
        int pos = atomicAdd(&hist[p >> 18], 1);
        adj[pos] = (int)(p & 0x3FFFFu);
    }
}

// ---------------- MFMA projection (layer 1): packed weights, no LDS ----------
template<int DIN, int DOUT>
__global__ __launch_bounds__(256) void proj_mfma(const float* __restrict__ H,
                                                 const __bf16* __restrict__ Wlb,
                                                 const __bf16* __restrict__ Wrh,
                                                 const __bf16* __restrict__ Wrl,
                                                 const float* __restrict__ bias,
                                                 unsigned short* __restrict__ Pl,
                                                 float* __restrict__ R, int N) {
    constexpr int COLT = DOUT / 16;
    const int wave = threadIdx.x >> 6, lane = threadIdx.x & 63;
    const int quad = lane >> 4, l16 = lane & 15;
    const int n0 = (blockIdx.x * 4 + wave) * 16;
    int arow = n0 + l16;
    if (arow >= N) arow = N - 1;
    const float* hrow = H + (size_t)arow * DIN;

    f32x4 zero = {0.f, 0.f, 0.f, 0.f};
    f32x4 accP[COLT], accR[COLT];
    #pragma unroll
    for (int t = 0; t < COLT; ++t) { accP[t] = zero; accR[t] = zero; }

    for (int k0 = 0; k0 < DIN; k0 += 32) {
        const float* hp = hrow + k0 + quad * 8;
        float4 h0 = *(const float4*)hp;
        float4 h1 = *(const float4*)(hp + 4);
        float hv[8] = {h0.x, h0.y, h0.z, h0.w, h1.x, h1.y, h1.z, h1.w};
        bf16x8 ahi, alo;
        #pragma unroll
        for (int j = 0; j < 8; ++j) {
            __bf16 hb = (__bf16)hv[j];
            ahi[j] = hb;
            alo[j] = (__bf16)(hv[j] - (float)hb);
        }
        const int u = (k0 >> 3) + quad;           // packed k-chunk index
        #pragma unroll
        for (int t = 0; t < COLT; ++t) {
            const int c = t * 16 + l16;
            const int wpos = (u * DOUT + c) * 8;  // lanes c=0..15 contiguous
            bf16x8 bl  = *(const bf16x8*)&Wlb[wpos];
            bf16x8 brh = *(const bf16x8*)&Wrh[wpos];
            bf16x8 brl = *(const bf16x8*)&Wrl[wpos];
            accP[t] = __builtin_amdgcn_mfma_f32_16x16x32_bf16(ahi, bl,  accP[t], 0, 0, 0);
            accR[t] = __builtin_amdgcn_mfma_f32_16x16x32_bf16(ahi, brh, accR[t], 0, 0, 0);
            accR[t] = __builtin_amdgcn_mfma_f32_16x16x32_bf16(ahi, brl, accR[t], 0, 0, 0);
            accR[t] = __builtin_amdgcn_mfma_f32_16x16x32_bf16(alo, brh, accR[t], 0, 0, 0);
        }
    }
    // C/D layout: col = lane&15, row = quad*4 + reg  [m89-verified]
    #pragma unroll
    for (int t = 0; t < COLT; ++t) {
        const int c = t * 16 + l16;
        const float bc = bias[c];
        #pragma unroll
        for (int r = 0; r < 4; ++r) {
            int node = n0 + quad * 4 + r;
            if (node < N) {
                Pl[(size_t)node * DOUT + c] = f2bf_rne(accP[t][r]);
                R[(size_t)node * DOUT + c] = accR[t][r] + bc;
            }
        }
    }
}

// ---------------- fused gather + next-layer projection ----------------
// gather phase: h[n] = relu( mean_j P[adj] + Rres[n] )   (h staged in LDS)
// proj phase:   Pout[n] = bf16( h W_l^T ),  Rout[n] = h W_r^T + b  (MFMA)
template<int D, int DP>
__global__ __launch_bounds__(256, 8) void gather_proj(const unsigned short* __restrict__ P,
                                                      const int* __restrict__ rowptr,
                                                      const int* __restrict__ adj,
                                                      const float* __restrict__ Rres,
                                                      const __bf16* __restrict__ Wlb,
                                                      const __bf16* __restrict__ Wrh,
                                                      const __bf16* __restrict__ Wrl,
                                                      const float* __restrict__ bias,
                                                      unsigned short* __restrict__ Pout,
                                                      float* __restrict__ Rout, int N) {
    constexpr int L   = D / 4;     // uint2s (4 bf16) per node row
    constexpr int S   = 64 / L;    // nodes concurrently per wave
    constexpr int M   = 4;         // sequential nodes per subgroup
    constexpr int NPW = S * M;     // nodes per wave
    constexpr int NPB = NPW * 4;   // nodes per block (4 waves)
    constexpr int SP  = D + 4;     // LDS row stride (floats, 16B-aligned, pad)
    constexpr int COLT = DP / 16;
    __shared__ __align__(16) float hstage[NPB * SP];

    const int wave = threadIdx.x >> 6, lane = threadIdx.x & 63;
    const int sub = lane / L, cl = lane % L;
    const uint2* __restrict__ P2 = (const uint2*)P;
    const f32x4* __restrict__ R4 = (const f32x4*)Rres;
    const int base = blockIdx.x * NPB + wave * NPW + sub;

    // ---- gather phase ----
    #pragma unroll 1
    for (int m = 0; m < M; ++m) {
        const int n = base + m * S;
        const int lrow = wave * NPW + sub + m * S;   // local row in block
        f32x4 o = {0.f, 0.f, 0.f, 0.f};
        if (n < N) {
            int beg = rowptr[n], end = rowptr[n + 1];
            float4 a0 = {0, 0, 0, 0}, a1 = {0, 0, 0, 0}, a2 = {0, 0, 0, 0}, a3 = {0, 0, 0, 0};
            int j = beg;
            while (j < end && (j & 3)) { bfacc(a0, P2[adj[j] * L + cl]); ++j; }
            for (; j + 8 <= end; j += 8) {
                int4 sA = *(const int4*)(adj + j);
                int4 sB = *(const int4*)(adj + j + 4);
                uint2 p0 = P2[sA.x * L + cl];
                uint2 p1 = P2[sA.y * L + cl];
                uint2 p2 = P2[sA.z * L + cl];
                uint2 p3 = P2[sA.w * L + cl];
                uint2 p4 = P2[sB.x * L + cl];
                uint2 p5 = P2[sB.y * L + cl];
                uint2 p6 = P2[sB.z * L + cl];
                uint2 p7 = P2[sB.w * L + cl];
                bfacc(a0, p0); bfacc(a1, p1); bfacc(a2, p2); bfacc(a3, p3);
                bfacc(a0, p4); bfacc(a1, p5); bfacc(a2, p6); bfacc(a3, p7);
            }
            if (j + 4 <= end) {
                int4 sA = *(const int4*)(adj + j);
                bfacc(a0, P2[sA.x * L + cl]);
                bfacc(a1, P2[sA.y * L + cl]);
                bfacc(a2, P2[sA.z * L + cl]);
                bfacc(a3, P2[sA.w * L + cl]);
                j += 4;
            }
            for (; j < end; ++j) bfacc(a0, P2[adj[j] * L + cl]);
            int deg = end - beg;
            float inv = deg > 0 ? 1.0f / (float)deg : 0.0f;
            f32x4 r = R4[(size_t)n * L + cl];
            o.x = fmaxf((a0.x + a1.x + a2.x + a3.x) * inv + r.x, 0.0f);
            o.y = fmaxf((a0.y + a1.y + a2.y + a3.y) * inv + r.y, 0.0f);
            o.z = fmaxf((a0.z + a1.z + a2.z + a3.z) * inv + r.z, 0.0f);
            o.w = fmaxf((a0.w + a1.w + a2.w + a3.w) * inv + r.w, 0.0f);
        }
        *(f32x4*)&hstage[lrow * SP + cl * 4] = o;
    }
    __syncthreads();

    // ---- proj phase: NPB nodes, DIN=D -> DOUT=DP, A from LDS, W packed ----
    const int quad = lane >> 4, l16 = lane & 15;
    f32x4 zero = {0.f, 0.f, 0.f, 0.f};
    #pragma unroll
    for (int tile = 0; tile < NPB / 64; ++tile) {
        const int trow0 = wave * NPW + tile * 16;     // tile's first local row
        f32x4 accP[COLT], accR[COLT];
        #pragma unroll
        for (int t = 0; t < COLT; ++t) { accP[t] = zero; accR[t] = zero; }
        #pragma unroll
        for (int k0 = 0; k0 < D; k0 += 32) {
            const int kk = k0 + quad * 8;
            const float* hp = &hstage[(trow0 + l16) * SP + kk];
            f32x4 h0 = *(const f32x4*)hp;
            f32x4 h1 = *(const f32x4*)(hp + 4);
            float hv[8] = {h0.x, h0.y, h0.z, h0.w, h1.x, h1.y, h1.z, h1.w};
            bf16x8 ahi, alo;
            #pragma unroll
            for (int j = 0; j < 8; ++j) {
                __bf16 hb = (__bf16)hv[j];
                ahi[j] = hb;
                alo[j] = (__bf16)(hv[j] - (float)hb);
            }
            const int u = (k0 >> 3) + quad;           // packed k-chunk index
            #pragma unroll
            for (int t = 0; t < COLT; ++t) {
                const int c = t * 16 + l16;
                const int wpos = (u * DP + c) * 8;    // lanes c=0..15 contiguous
                bf16x8 bl  = *(const bf16x8*)&Wlb[wpos];
                bf16x8 brh = *(const bf16x8*)&Wrh[wpos];
                bf16x8 brl = *(const bf16x8*)&Wrl[wpos];
                accP[t] = __builtin_amdgcn_mfma_f32_16x16x32_bf16(ahi, bl,  accP[t], 0, 0, 0);
                accR[t] = __builtin_amdgcn_mfma_f32_16x16x32_bf16(ahi, brh, accR[t], 0, 0, 0);
                accR[t] = __builtin_amdgcn_mfma_f32_16x16x32_bf16(ahi, brl, accR[t], 0, 0, 0);
                accR[t] = __builtin_amdgcn_mfma_f32_16x16x32_bf16(alo, brh, accR[t], 0, 0, 0);
            }
        }
        // C/D layout: col = lane&15, row = quad*4 + reg  [m89-verified]
        #pragma unroll
        for (int t = 0; t < COLT; ++t) {
            const int c = t * 16 + l16;
            const float bc = bias[c];
            #pragma unroll
            for (int r = 0; r < 4; ++r) {
                int node = blockIdx.x * NPB + trow0 + quad * 4 + r;
                if (node < N) {
                    Pout[(size_t)node * DP + c] = f2bf_rne(accP[t][r]);
                    Rout[(size_t)node * DP + c] = accR[t][r] + bc;
                }
            }
        }
    }
}

// ---------------- final gather + linear heads (layer 3) ----------------

template<int DOUT> struct GatherCfg {
    static constexpr int L   = DOUT / 4;   // uint2s (4 bf16) per node row
    static constexpr int S   = 64 / L;     // nodes concurrently per wave
    static constexpr int M   = 4;          // sequential nodes per subgroup
    static constexpr int NPW = S * M;
    static constexpr int NPB = NPW * 4;    // 4 waves/block
};

template<int DOUT>
__global__ __launch_bounds__(256, 8) void gather_head(const unsigned short* __restrict__ P,
                                                      const int* __restrict__ rowptr,
                                                      const int* __restrict__ adj,
                                                      const float* __restrict__ Rres, int N,
                                                      const float* __restrict__ Wreg,
                                                      const float* __restrict__ breg,
                                                      const float* __restrict__ Wcls,
                                                      const float* __restrict__ bcls,
                                                      float* __restrict__ out) {
    using C = GatherCfg<DOUT>;
    constexpr int L = C::L, S = C::S, M = C::M;
    constexpr int NPW = C::NPW, NPB = C::NPB;
    const int wave = threadIdx.x >> 6, lane = threadIdx.x & 63;
    const int sub = lane / L, cl = lane % L;
    const uint2* __restrict__ P2 = (const uint2*)P;
    const float4* __restrict__ R4 = (const float4*)Rres;
    const int base = blockIdx.x * NPB + wave * NPW + sub;
    #pragma unroll 1
    for (int m = 0; m < M; ++m) {
        int n = base + m * S;
        if (n >= N) continue;
        int beg = rowptr[n], end = rowptr[n + 1];
        float4 a0 = {0, 0, 0, 0}, a1 = {0, 0, 0, 0}, a2 = {0, 0, 0, 0}, a3 = {0, 0, 0, 0};
        int j = beg;
        while (j < end && (j & 3)) { bfacc(a0, P2[adj[j] * L + cl]); ++j; }
        for (; j + 8 <= end; j += 8) {
            int4 sA = *(const int4*)(adj + j);
            int4 sB = *(const int4*)(adj + j + 4);
            uint2 p0 = P2[sA.x * L + cl];
            uint2 p1 = P2[sA.y * L + cl];
            uint2 p2 = P2[sA.z * L + cl];
            uint2 p3 = P2[sA.w * L + cl];
            uint2 p4 = P2[sB.x * L + cl];
            uint2 p5 = P2[sB.y * L + cl];
            uint2 p6 = P2[sB.z * L + cl];
            uint2 p7 = P2[sB.w * L + cl];
            bfacc(a0, p0); bfacc(a1, p1); bfacc(a2, p2); bfacc(a3, p3);
            bfacc(a0, p4); bfacc(a1, p5); bfacc(a2, p6); bfacc(a3, p7);
        }
        if (j + 4 <= end) {
            int4 sA = *(const int4*)(adj + j);
            bfacc(a0, P2[sA.x * L + cl]);
            bfacc(a1, P2[sA.y * L + cl]);
            bfacc(a2, P2[sA.z * L + cl]);
            bfacc(a3, P2[sA.w * L + cl]);
            j += 4;
        }
        for (; j < end; ++j) bfacc(a0, P2[adj[j] * L + cl]);
        int deg = end - beg;
        float inv = deg > 0 ? 1.0f / (float)deg : 0.0f;
        float4 r = R4[(size_t)n * L + cl];
        float4 o;
        o.x = fmaxf((a0.x + a1.x + a2.x + a3.x) * inv + r.x, 0.0f);
        o.y = fmaxf((a0.y + a1.y + a2.y + a3.y) * inv + r.y, 0.0f);
        o.z = fmaxf((a0.z + a1.z + a2.z + a3.z) * inv + r.z, 0.0f);
        o.w = fmaxf((a0.w + a1.w + a2.w + a3.w) * inv + r.w, 0.0f);
        // fused linear heads: per-lane partial dot (4 of 16 features),
        // 2-step shfl reduce across the 4-lane subgroup
        float4 wr = ((const float4*)Wreg)[cl];
        float4 wc = ((const float4*)Wcls)[cl];
        float pr = o.x * wr.x + o.y * wr.y + o.z * wr.z + o.w * wr.w;
        float pc = o.x * wc.x + o.y * wc.y + o.z * wc.z + o.w * wc.w;
        pr += __shfl_xor(pr, 1); pr += __shfl_xor(pr, 2);
        pc += __shfl_xor(pc, 1); pc += __shfl_xor(pc, 2);
        if (cl == 0) {
            out[n] = pr + breg[0];
            out[(size_t)N + n] = pc + bcls[0];
        }
    }
}

extern "C" void kernel_launch(void* const* d_in, const int* in_sizes, int n_in,
                              void* d_out, int out_size, void* d_ws, size_t ws_size,
                              hipStream_t stream) {
    const float* x    = (const float*)d_in[0];
    const int*   ei   = (const int*)d_in[1];
    const float* W1l  = (const float*)d_in[2];
    const float* b1l  = (const float*)d_in[3];
    const float* W1r  = (const float*)d_in[4];
    const float* W2l  = (const float*)d_in[5];
    const float* b2l  = (const float*)d_in[6];
    const float* W2r  = (const float*)d_in[7];
    const float* W3l  = (const float*)d_in[8];
    const float* b3l  = (const float*)d_in[9];
    const float* W3r  = (const float*)d_in[10];
    const float* Wreg = (const float*)d_in[11];
    const float* breg = (const float*)d_in[12];
    const float* Wcls = (const float*)d_in[13];
    const float* bcls = (const float*)d_in[14];

    const int N = in_sizes[0] / 128;
    const int E = in_sizes[1] / 2;
    const int* src = ei;
    const int* dst = ei + E;

    char* ws = (char*)d_ws;
    size_t off = 0;
    auto alloc = [&](size_t bytes) -> void* {
        void* p = ws + off;
        off += (bytes + 255) & ~(size_t)255;
        return p;
    };
    int*   rowptr = (int*)alloc((size_t)(N + 1) * 4);
    int*   bcnt   = (int*)alloc(1024);
    int*   bcur   = (int*)alloc(1024);
    int*   boff   = (int*)alloc(1028);
    int*   adj    = (int*)alloc((size_t)E * 4);
    __bf16* W16   = (__bf16*)alloc(32256 * 2);           // pre-converted packed weights
    unsigned short* A1 = (unsigned short*)alloc((size_t)N * 64 * 2);  // P1 bf16; A3 aliases
    unsigned short* A2 = (unsigned short*)alloc((size_t)N * 32 * 2);  // P2 bf16
    float* B      = (float*)alloc((size_t)N * 64 * 4);  // R1; doubles as T during CSR build
    float* C      = (float*)alloc((size_t)N * 32 * 4);  // R2
    float* D      = (float*)alloc((size_t)N * 16 * 4);  // R3
    int*   T      = (int*)B;                             // packed edges, E*4B <= N*64*4B
    unsigned short* A3 = A1;                             // P3 bf16 (A1 dead after layer 2)

    const int NBK = (N + 1023) >> 10;     // buckets (196; must be <= 256)

    // ---- weight pre-conversion (independent of everything else) ----
    k_wprep<<<42, 256, 0, stream>>>(W1l, W1r, W2l, W2r, W3l, W3r, W16);

    // ---- CSR build ----
    hipMemsetAsync(bcnt, 0, 1024, stream);
    k_bcount<<<1024, 256, 0, stream>>>(dst, E, N, bcnt);
    k_bscan<<<1, 256, 0, stream>>>(bcnt, boff, bcur, NBK, E);
    k_bucket<<<(E + BTILE - 1) / BTILE, 256, 0, stream>>>(src, dst, E, N, boff, bcur, T, NBK);
    k_csr<<<NBK, 1024, 0, stream>>>(T, boff, rowptr, adj, N, E);

    const int PB = 64;   // nodes per proj_mfma block (4 waves x 16)

    // ---- layer 1 projection: x (128) -> P1,R1 (64) ----
    proj_mfma<128, 64><<<(N + PB - 1) / PB, 256, 0, stream>>>(
        x, W16, W16 + 8192, W16 + 16384, b1l, A1, B, N);
    // ---- layer 1 gather + layer 2 projection fused: h1 never hits HBM ----
    gather_proj<64, 32><<<(N + 63) / 64, 256, 0, stream>>>(
        A1, rowptr, adj, B, W16 + 24576, W16 + 26624, W16 + 28672, b2l, A2, C, N);
    // ---- layer 2 gather + layer 3 projection fused: h2 never hits HBM ----
    gather_proj<32, 16><<<(N + 127) / 128, 256, 0, stream>>>(
        A2, rowptr, adj, C, W16 + 30720, W16 + 31232, W16 + 31744, b3l, A3, D, N);
    // ---- layer 3 gather + linear heads fused ----
    constexpr int G16 = GatherCfg<16>::NPB;
    gather_head<16><<<(N + G16 - 1) / G16, 256, 0, stream>>>(
        A3, rowptr, adj, D, N, Wreg, breg, Wcls, bcls, (float*)d_out);
}